// Round 8
// baseline (99.624 us; speedup 1.0000x reference)
//
#include <hip/hip_runtime.h>
#include <hip/hip_bf16.h>

#define IN_CNT 64
#define FEAT   1024
#define BATCH  256

#define BM 256
#define BN 128
#define BK 32
#define KT (FEAT / BK)   // 32 K-tiles

typedef __attribute__((ext_vector_type(4))) float f32x4;
typedef __attribute__((ext_vector_type(8))) short bf16x8;   // 8 bf16 = one MFMA A/B frag

__device__ __forceinline__ short f2bf(float f) {
    __hip_bfloat16 h = __float2bfloat16(f);
    return __builtin_bit_cast(short, h);
}

__device__ __forceinline__ bf16x8 pack8(f32x4 a, f32x4 b) {
    bf16x8 v;
    v[0] = f2bf(a[0]); v[1] = f2bf(a[1]); v[2] = f2bf(a[2]); v[3] = f2bf(a[3]);
    v[4] = f2bf(b[0]); v[5] = f2bf(b[1]); v[6] = f2bf(b[2]); v[7] = f2bf(b[3]);
    return v;
}

__device__ __forceinline__ void barrier_lgkm() {
    asm volatile("s_waitcnt lgkmcnt(0)" ::: "memory");
    __builtin_amdgcn_s_barrier();
    asm volatile("" ::: "memory");
}

// async global->LDS DMA, 16B per lane. LDS dest = wave-uniform base + lane*16.
__device__ __forceinline__ void gload16(const float* g, float* l) {
    __builtin_amdgcn_global_load_lds(
        (const __attribute__((address_space(1))) void*)g,
        (__attribute__((address_space(3))) void*)l, 16, 0, 0);
}

// 2 blocks/CU discriminator: BM=256 x BN=128 tile, 4 waves, 80 KB LDS exact.
// A(x): reg-staged bf16, double-buffered. B(W): fp32 DMA, triple-ring, 2-deep.
__global__ __launch_bounds__(256, 2)
void split_linear_kernel(const float* __restrict__ x,
                         const float* __restrict__ W,
                         float* __restrict__ out)
{
    // smem carve (80 KB exactly):
    //   A bf16 [2][128 superrows][8 slots of 8 bf16], slot ^= (sr&7) : 32 KB
    //   B f32  [3][128 rows][8 granules of 4 f32],  gran ^= (r&7)    : 48 KB
    // epilogue reuses front as float[64][132] (33.8 KB).
    __shared__ __align__(16) char smem[81920];
    short* Alds = (short*)smem;             // 16384 shorts
    float* Blds = (float*)(smem + 32768);   // 12288 floats
    float* elds = (float*)smem;

    const int tid = threadIdx.x;

    // bijective XCD swizzle (512 % 8 == 0): each gi's 8 N-blocks on one XCD.
    const int bid = blockIdx.x;
    const int swz = ((bid & 7) << 6) | (bid >> 3);
    const int gi   = swz >> 3;            // 0..63
    const int ncol = (swz & 7) << 7;      // 0..896 step 128

    const int lane = tid & 63;
    const int wid  = tid >> 6;            // 0..3
    const int wm   = wid >> 1;            // 0..1
    const int wn   = wid & 1;             // 0..1
    const int lr   = lane & 15;
    const int lh   = lane >> 4;

    // ---- A staging map (R6-proven 8-superrow x 8-slot instr shape):
    // pass p: slot id = p*256+tid; sr = id>>3, sq = tid&7.
    // slot (sr,sq) holds row r = 2*sr + (sq>>2), k-oct = sq&3 (8 floats).
    const int sq   = tid & 7;
    const int asr0 = tid >> 3;                 // + p*32
    const int arow = (asr0 << 1) + (sq >> 2);  // row for p=0 (+ p*64)
    const float* Aglob = x + ((size_t)arow * IN_CNT + gi) * FEAT + (sq & 3) * 8;

    // ---- B DMA source coords (R6-proven): lane L -> row L>>3, granule (L&7)^(L>>3)
    const int lrow = lane >> 3;
    const int lgr  = (lane & 7) ^ lrow;
    const float* Bsrc = W + ((size_t)gi * FEAT + ncol + lrow) * FEAT + lgr * 4;

    f32x4 aA[4][2];                      // A staging regs: 8 f32x4
    f32x4 acc[8][4];
#pragma unroll
    for (int m = 0; m < 8; ++m)
#pragma unroll
        for (int n = 0; n < 4; ++n)
            acc[m][n] = (f32x4){0.f, 0.f, 0.f, 0.f};

    auto LOAD_A = [&](int kt) {
#pragma unroll
        for (int p = 0; p < 4; ++p) {
            const float* q = Aglob + (size_t)p * (64 * IN_CNT * FEAT) + (size_t)kt * BK;
            aA[p][0] = *(const f32x4*)q;
            aA[p][1] = *(const f32x4*)(q + 4);
        }
    };
    auto WRITE_A = [&](int ab) {
        short* base = Alds + ab * 8192;
#pragma unroll
        for (int p = 0; p < 4; ++p) {
            const int sr = asr0 + p * 32;
            *(bf16x8*)&base[sr * 64 + ((sq ^ (sr & 7)) << 3)] = pack8(aA[p][0], aA[p][1]);
        }
    };
    // B tile = 16 chunks (8 rows x 1 KB); wave takes 4
    auto DMA_B = [&](int kt, int q) {
        float* base = Blds + q * 4096;
        const float* b0 = Bsrc + (size_t)kt * BK;
#pragma unroll
        for (int i = 0; i < 4; ++i) {
            const int c = wid * 4 + i;
            gload16(b0 + (size_t)c * (8 * FEAT), base + c * 256);
        }
    };

    // fragment read offsets
    const int bsl0 = ((2 * lh)     ^ (lr & 7)) << 2;   // B: float offs of 2 granules
    const int bsl1 = ((2 * lh + 1) ^ (lr & 7)) << 2;

    auto COMPUTE = [&](int ab, int q) {
        const float* bufB = Blds + q * 4096;
        const short* bufA = Alds + ab * 8192;
        bf16x8 bfr[4];
#pragma unroll
        for (int nf = 0; nf < 4; ++nf) {
            const float* rp = bufB + (wn * 64 + nf * 16 + lr) * 32;
            bfr[nf] = pack8(*(const f32x4*)(rp + bsl0), *(const f32x4*)(rp + bsl1));
        }
        __builtin_amdgcn_s_setprio(1);
#pragma unroll
        for (int mf = 0; mf < 8; ++mf) {
            const int r  = wm * 128 + mf * 16 + lr;
            const int sr = r >> 1;
            bf16x8 af = *(const bf16x8*)&bufA[sr * 64
                            + (((((r & 1) << 2) + lh) ^ (sr & 7)) << 3)];
#pragma unroll
            for (int nf = 0; nf < 4; ++nf)
                acc[mf][nf] = __builtin_amdgcn_mfma_f32_16x16x32_bf16(
                    af, bfr[nf], acc[mf][nf], 0, 0, 0);
        }
        __builtin_amdgcn_s_setprio(0);
    };

    // ---- prologue: B(0)->ring0, B(1)->ring1 in flight; A(0) staged
    DMA_B(0, 0);
    DMA_B(1, 1);
    LOAD_A(0);
    WRITE_A(0);
    asm volatile("s_waitcnt vmcnt(4)" ::: "memory");   // B(0) landed; B(1) in flight
    __builtin_amdgcn_s_barrier();
    asm volatile("" ::: "memory");

    // ---- main loop
    int q0 = 0, q1 = 1, q2 = 2;
    int ab = 0;
    for (int t = 0; t < KT; ++t) {
        if (t + 1 < KT) LOAD_A(t + 1);          // covered by compute
        if (t + 2 < KT) DMA_B(t + 2, q2);       // 2-deep W prefetch
        COMPUTE(ab, q0);
        if (t + 1 < KT) WRITE_A(ab ^ 1);        // buf freed at entry barrier
        if (t + 2 < KT) {
            asm volatile("s_waitcnt vmcnt(4)" ::: "memory");   // B(t+1) landed
        } else {
            asm volatile("s_waitcnt vmcnt(0)" ::: "memory");
        }
        __builtin_amdgcn_s_barrier();
        asm volatile("" ::: "memory");
        const int tq = q0; q0 = q1; q1 = q2; q2 = tq;
        ab ^= 1;
    }

    // ---- epilogue: stripe-transpose -> contiguous stores (2 rows x 512B / instr)
    // C/D frag layout: col = lane&15 (n), row = lh*4 + j (m)  [m89-verified]
#define ELD 132
#pragma unroll
    for (int s = 0; s < 4; ++s) {               // stripes of 64 m-rows
        barrier_lgkm();
        if (wm == (s >> 1)) {
            const int mfb = (s & 1) * 4;
#pragma unroll
            for (int f = 0; f < 4; ++f)
#pragma unroll
                for (int nf = 0; nf < 4; ++nf)
#pragma unroll
                    for (int j = 0; j < 4; ++j)
                        elds[(f * 16 + lh * 4 + j) * ELD + wn * 64 + nf * 16 + lr]
                            = acc[mfb + f][nf][j];
        }
        barrier_lgkm();
#pragma unroll
        for (int rr = 0; rr < 8; ++rr) {        // wave covers rows wid*16..+15
            const int rowl = wid * 16 + rr * 2 + (lane >> 5);
            f32x4 v = *(const f32x4*)&elds[rowl * ELD + (lane & 31) * 4];
            const int m = s * 64 + rowl;
            *(f32x4*)&out[((size_t)m * IN_CNT + gi) * FEAT + ncol + (lane & 31) * 4] = v;
        }
    }
#undef ELD
}

extern "C" void kernel_launch(void* const* d_in, const int* in_sizes, int n_in,
                              void* d_out, int out_size, void* d_ws, size_t ws_size,
                              hipStream_t stream) {
    const float* x   = (const float*)d_in[0];
    const float* W   = (const float*)d_in[1];
    float*       out = (float*)d_out;

    dim3 grid(IN_CNT * (FEAT / BN));   // 512 blocks: 2 per CU
    dim3 block(256);
    hipLaunchKernelGGL(split_linear_kernel, grid, block, 0, stream, x, W, out);
}

// Round 9
// 95.501 us; speedup vs baseline: 1.0432x; 1.0432x over previous
//
#include <hip/hip_runtime.h>
#include <hip/hip_bf16.h>

#define IN_CNT 64
#define FEAT   1024
#define BATCH  256

#define BM 256
#define BN 256
#define BK 32
#define KT (FEAT / BK)   // 32 K-tiles

typedef __attribute__((ext_vector_type(4))) float f32x4;
typedef __attribute__((ext_vector_type(8))) short bf16x8;   // 8 bf16 = one MFMA A/B frag

__device__ __forceinline__ short f2bf(float f) {
    __hip_bfloat16 h = __float2bfloat16(f);
    return __builtin_bit_cast(short, h);
}

__device__ __forceinline__ bf16x8 pack8(f32x4 a, f32x4 b) {
    bf16x8 v;
    v[0] = f2bf(a[0]); v[1] = f2bf(a[1]); v[2] = f2bf(a[2]); v[3] = f2bf(a[3]);
    v[4] = f2bf(b[0]); v[5] = f2bf(b[1]); v[6] = f2bf(b[2]); v[7] = f2bf(b[3]);
    return v;
}

// barrier + LDS drain only; vmcnt managed manually (counted, never 0 mid-loop)
__device__ __forceinline__ void barrier_lgkm() {
    asm volatile("s_waitcnt lgkmcnt(0)" ::: "memory");
    __builtin_amdgcn_s_barrier();
    asm volatile("" ::: "memory");
}

// async global->LDS DMA, 16B per lane. LDS dest = wave-uniform base + lane*16.
__device__ __forceinline__ void gload16(const float* g, float* l) {
    __builtin_amdgcn_global_load_lds(
        (const __attribute__((address_space(1))) void*)g,
        (__attribute__((address_space(3))) void*)l, 16, 0, 0);
}

__global__ __launch_bounds__(512, 2)
void split_linear_kernel(const float* __restrict__ x,
                         const float* __restrict__ W,
                         float* __restrict__ out)
{
    // fp32 tiles in LDS: 2 bufs x (A 256x32 = 32KB + B 32KB) = 128 KB.
    // buf b at float offset b*16384; A +0, B +8192. Row = 32 floats = 128 B,
    // 8 granules of 16 B. Swizzle: LDS slot s of row r holds global granule
    // s ^ (r&7) (applied on the DMA *source* address; DMA writes linearly).
    __shared__ __align__(16) float lds[32768];

    const int tid = threadIdx.x;

    // bijective XCD swizzle (256 % 8 == 0): the 4 same-gi blocks share one XCD L2.
    const int bid = blockIdx.x;
    const int swz = ((bid & 7) << 5) | (bid >> 3);
    const int gi   = swz >> 2;            // 0..63
    const int nidx = swz & 3;
    const int ncol = nidx << 8;           // 0/256/512/768

    // K-phase stagger: same-gi blocks process K-tiles rotated by 1 tile each,
    // so x-tile misses are taken by the leader only; followers hit L2/L3.
    const int jrot = nidx;

    const int lane = tid & 63;
    const int wid  = tid >> 6;
    const int wm   = wid >> 2;            // 0..1
    const int wn   = wid & 3;             // 0..3
    const int lr   = lane & 15;
    const int lh   = lane >> 4;

    // ---- DMA source coords: chunk = 8 rows x 8 granules; lane L -> row L>>3,
    // fetches granule (L&7)^(L>>3) so LDS slot (L&7) holds the swizzled granule.
    const int lrow = lane >> 3;                 // 0..7
    const int lgr  = (lane & 7) ^ lrow;         // pre-swizzled source granule
    const float* Asrc = x + ((size_t)lrow * IN_CNT + gi) * FEAT + lgr * 4;
    const float* Bsrc = W + ((size_t)gi * FEAT + ncol + lrow) * FEAT + lgr * 4;

    f32x4 acc[8][4];
#pragma unroll
    for (int m = 0; m < 8; ++m)
#pragma unroll
        for (int n = 0; n < 4; ++n)
            acc[m][n] = (f32x4){0.f, 0.f, 0.f, 0.f};

    // issue one tile's DMA: W (cold, long pole) first, then A (warm).
    auto ISSUE = [&](int kt, int b) {
        float* base = lds + b * 16384;
        const float* a0 = Asrc + (size_t)kt * BK;
        const float* b0 = Bsrc + (size_t)kt * BK;
#pragma unroll
        for (int i = 0; i < 4; ++i) {
            const int c = wid * 4 + i;          // chunk 0..31 (8 rows each)
            gload16(b0 + (size_t)c * (8 * FEAT),          base + 8192 + c * 256);
        }
#pragma unroll
        for (int i = 0; i < 4; ++i) {
            const int c = wid * 4 + i;
            gload16(a0 + (size_t)c * (8 * IN_CNT * FEAT), base + c * 256);
        }
    };

    // read fp32 frag (k = lh*8 .. lh*8+7) from swizzled LDS row, cvt to bf16
    const int sl0 = ((2 * lh)     ^ (lr & 7)) << 2;   // float offsets of the 2 slots
    const int sl1 = ((2 * lh + 1) ^ (lr & 7)) << 2;

    auto COMPUTE = [&](int b) {
        const float* bufA = lds + b * 16384;
        const float* bufB = bufA + 8192;
        bf16x8 bfr[4];
#pragma unroll
        for (int nf = 0; nf < 4; ++nf) {
            const float* rp = bufB + (wn * 64 + nf * 16 + lr) * 32;
            bfr[nf] = pack8(*(const f32x4*)(rp + sl0), *(const f32x4*)(rp + sl1));
        }
        __builtin_amdgcn_s_setprio(1);
#pragma unroll
        for (int mf = 0; mf < 8; ++mf) {
            const float* rp = bufA + (wm * 128 + mf * 16 + lr) * 32;
            bf16x8 af = pack8(*(const f32x4*)(rp + sl0), *(const f32x4*)(rp + sl1));
#pragma unroll
            for (int nf = 0; nf < 4; ++nf)
                acc[mf][nf] = __builtin_amdgcn_mfma_f32_16x16x32_bf16(
                    af, bfr[nf], acc[mf][nf], 0, 0, 0);
        }
        __builtin_amdgcn_s_setprio(0);
    };

    // ---- prologue: tiles jrot, jrot+1 in flight; wait tile jrot
    ISSUE(jrot, 0);
    ISSUE((jrot + 1) & (KT - 1), 1);
    asm volatile("s_waitcnt vmcnt(8)" ::: "memory");
    __builtin_amdgcn_s_barrier();
    asm volatile("" ::: "memory");

    // ---- main loop: compute k | barrier | issue k+2 into k's buf, wait k+1 | barrier
    for (int k = 0; k < KT; ++k) {
        const int b = k & 1;
        COMPUTE(b);
        barrier_lgkm();                        // all waves done reading buf b
        if (k + 2 < KT) {
            ISSUE((k + 2 + jrot) & (KT - 1), b);
            asm volatile("s_waitcnt vmcnt(8)" ::: "memory");   // tile k+1 landed
        } else {
            asm volatile("s_waitcnt vmcnt(0)" ::: "memory");   // tail drain
        }
        __builtin_amdgcn_s_barrier();
        asm volatile("" ::: "memory");
    }

    // ---- epilogue: stripe-transpose through LDS -> contiguous f32x4 stores.
    // C/D frag layout: col = lane&15 (n), row = lh*4 + j (m)  [m89-verified]
#define ELD 260
    float* elds = lds;   // 64 rows x 260 floats = 66.6 KB scratch (have 128 KB)
#pragma unroll
    for (int s = 0; s < 4; ++s) {               // 4 stripes of 64 m-rows
        barrier_lgkm();                          // previous stripe fully read
        if (wm == (s >> 1)) {
            const int mfb = (s & 1) * 4;
#pragma unroll
            for (int f = 0; f < 4; ++f)
#pragma unroll
                for (int nf = 0; nf < 4; ++nf)
#pragma unroll
                    for (int j = 0; j < 4; ++j)
                        elds[(f * 16 + lh * 4 + j) * ELD + wn * 64 + nf * 16 + lr]
                            = acc[mfb + f][nf][j];
        }
        barrier_lgkm();
#pragma unroll
        for (int rr = 0; rr < 8; ++rr) {         // wave w stores rows w*8..w*8+7
            const int rowl = wid * 8 + rr;
            f32x4 v = *(const f32x4*)&elds[rowl * ELD + lane * 4];
            const int m = s * 64 + rowl;
            *(f32x4*)&out[((size_t)m * IN_CNT + gi) * FEAT + ncol + lane * 4] = v;
        }
    }
#undef ELD
}

extern "C" void kernel_launch(void* const* d_in, const int* in_sizes, int n_in,
                              void* d_out, int out_size, void* d_ws, size_t ws_size,
                              hipStream_t stream) {
    const float* x   = (const float*)d_in[0];
    const float* W   = (const float*)d_in[1];
    float*       out = (float*)d_out;

    dim3 grid(IN_CNT * (FEAT / BN));   // 256 blocks: one 256x256 tile each
    dim3 block(512);
    hipLaunchKernelGGL(split_linear_kernel, grid, block, 0, stream, x, W, out);
}